// Round 11
// baseline (464.872 us; speedup 1.0000x reference)
//
#include <hip/hip_runtime.h>

namespace {

constexpr int T_STEPS = 1000;
constexpr int NB      = 4096;
constexpr float LOG2E = 1.4426950408889634f;

typedef float v2f __attribute__((ext_vector_type(2)));

__device__ __forceinline__ float fexp2(float x) { return __builtin_amdgcn_exp2f(x); }
__device__ __forceinline__ float frcp(float x)  { return __builtin_amdgcn_rcpf(x); }
__device__ __forceinline__ v2f mkv2(float a, float b) { v2f r; r.x = a; r.y = b; return r; }

__device__ __forceinline__ v2f pkfma(v2f a, v2f b, v2f c) {
#if __has_builtin(__builtin_elementwise_fma)
    return __builtin_elementwise_fma(a, b, c);   // v_pk_fma_f32
#else
    v2f r; r.x = fmaf(a.x, b.x, c.x); r.y = fmaf(a.y, b.y, c.y); return r;
#endif
}

// DPP on the VALU pipe (R4-HW-proven patterns).
template<int CTRL>
__device__ __forceinline__ float dppf(float v) {
    int i = __float_as_int(v);
    return __int_as_float(__builtin_amdgcn_update_dpp(i, i, CTRL, 0xF, 0xF, false));
}
// xor-16 within each 32-lane half (R4-HW-proven): BitMode (xor<<10)|(or<<5)|and
__device__ __forceinline__ float swzx16(float v) {
    return __int_as_float(__builtin_amdgcn_ds_swizzle(__float_as_int(v), 0x401F));
}

// W=32 quad scheme (R4-proven): one element per 32 lanes, 2 elem/wave,
// 2048 waves = 2 waves/SIMD (the TLP that hides the ~2.6cy/instr dependency
// latency measured in R9/R10). Lane q in [0,32): 16-row R=q>>4, j=q&15,
// quad qd=j>>2, gate g=q&3 (i,f,g,o); unit u=R*4+qd; weight row=g*8+u.
// All 4 lanes of a quad redundantly compute their unit's c/h.
// + pk_fma matvecs (R9/R10 A/B: pk >> scalar), v_rcp kept (Newton regressed),
// + in-lane L0/L1 pipelining (R8), + consume-then-reload 4-slot prefetch
// ring (R9 pattern: reload the SAME slot -> true distance-4 ~ 1600+ cy).
__global__ __launch_bounds__(256, 2)
void lstm_fused_kernel(
    const float* __restrict__ state, const float* __restrict__ dist,
    const float* __restrict__ e1W1, const float* __restrict__ e1b1,
    const float* __restrict__ e1W2, const float* __restrict__ e1b2,
    const float* __restrict__ e2W1, const float* __restrict__ e2b1,
    const float* __restrict__ e2W2, const float* __restrict__ e2b2,
    const float* __restrict__ Wih0, const float* __restrict__ Whh0,
    const float* __restrict__ bih0, const float* __restrict__ bhh0,
    const float* __restrict__ Wih1, const float* __restrict__ Whh1,
    const float* __restrict__ bih1, const float* __restrict__ bhh1,
    const float* __restrict__ decW, const float* __restrict__ decb,
    const float* __restrict__ finW, const float* __restrict__ finb,
    const float* __restrict__ fin2W, const float* __restrict__ fin2b,
    float* __restrict__ out)
{
    const int tid = (int)threadIdx.x;
    const int q   = tid & 31;
    const int n   = blockIdx.x * 8 + (tid >> 5);
    const int j   = q & 15;
    const int R   = q >> 4;
    const int qd  = j >> 2;
    const int g   = q & 3;         // gate (i,f,g,o)
    const int u   = R * 4 + qd;    // unit
    const int row = g * 8 + u;     // gate-matrix row

    // probe row_ror direction (R4-proven): h slot k -> unit pidx(k)
    const int pv  = __builtin_amdgcn_update_dpp(0, j, 0x121, 0xF, 0xF, true);
    const int sgn = (pv == ((j + 1) & 15)) ? 1 : -1;
    auto pidx = [&](int k) {
        const int rsel = (k < 4) ? R : (1 - R);
        return rsel * 4 + ((qd + sgn * (k & 3)) & 3);
    };

    const bool isG = (g == 2);
    const float scl = isG ? (-2.0f * LOG2E) : (-LOG2E);
    const float mul = isG ? 2.0f : 1.0f;
    const float add = isG ? -1.0f : 0.0f;
    const bool gb0 = (g & 1) != 0;
    const bool gb1 = (g & 2) != 0;

    // ---- packed weight rows (h-side and L1 x-side slot-permuted; R4 map) ----
    v2f wx0[4], wh0[4], wx1[4], wh1[4];
#pragma unroll
    for (int k = 0; k < 4; ++k) {
        const int k0 = 2 * k, k1 = 2 * k + 1;
        const int p0 = pidx(k0), p1 = pidx(k1);
        wx0[k] = mkv2(Wih0[row * 8 + k0] * scl, Wih0[row * 8 + k1] * scl);
        wh0[k] = mkv2(Whh0[row * 8 + p0] * scl, Whh0[row * 8 + p1] * scl);
        wx1[k] = mkv2(Wih1[row * 8 + p0] * scl, Wih1[row * 8 + p1] * scl);
        wh1[k] = mkv2(Whh1[row * 8 + p0] * scl, Whh1[row * 8 + p1] * scl);
    }
    const v2f vb0 = mkv2((bih0[row] + bhh0[row]) * scl, 0.0f);
    const v2f vb1 = mkv2((bih1[row] + bhh1[row]) * scl, 0.0f);

    // decoder (R4-proven): dec row dr=g, slot-permuted; head by quad parity
    const int dr = g;
    const int hsel = (q >> 2) & 1;
    v2f dwr2[4];
#pragma unroll
    for (int k = 0; k < 4; ++k)
        dwr2[k] = mkv2(decW[dr * 8 + pidx(2 * k)], decW[dr * 8 + pidx(2 * k + 1)]);
    const v2f vdb = mkv2(decb[dr], 0.0f);
    float fwp[4]; float fb;
    {
        const float* Wp = hsel ? fin2W : finW;
        const float* bp = hsel ? fin2b : finb;
#pragma unroll
        for (int jj = 0; jj < 4; ++jj) fwp[jj] = Wp[dr * 4 + ((dr + jj) & 3)];
        fb = bp[dr];
    }

    // ---------------- x slots: issue x(0..3) loads first ----------------
    const float4* dp = reinterpret_cast<const float4*>(dist) + (size_t)n * 2;
    constexpr size_t TS4 = (size_t)NB * 2;
    float4 x0a = dp[0 * TS4], x0b = dp[0 * TS4 + 1];
    float4 x1a = dp[1 * TS4], x1b = dp[1 * TS4 + 1];
    float4 x2a = dp[2 * TS4], x2b = dp[2 * TS4 + 1];
    float4 x3a = dp[3 * TS4], x3b = dp[3 * TS4 + 1];

    // ---------------- encoders (R4-verbatim; overlaps the loads) -------------
    float hE[8], hO[8], h1v[8];
    float c0, c1;
    {
        float s[16];
#pragma unroll
        for (int k = 0; k < 16; ++k) s[k] = state[n * 16 + k];
        float hm1[4], hm2[4];
#pragma unroll
        for (int m = 0; m < 4; ++m) {
            float a = e1b1[m], b = e2b1[m];
#pragma unroll
            for (int k = 0; k < 16; ++k) {
                a = fmaf(s[k], e1W1[m * 16 + k], a);
                b = fmaf(s[k], e2W1[m * 16 + k], b);
            }
            hm1[m] = fmaxf(a, 0.0f); hm2[m] = fmaxf(b, 0.0f);
        }
#pragma unroll
        for (int k = 0; k < 8; ++k) {
            const int p = pidx(k);
            float a = e1b2[p], b = e1b2[8 + p];
#pragma unroll
            for (int m = 0; m < 4; ++m) {
                a = fmaf(hm1[m], e1W2[p * 4 + m], a);
                b = fmaf(hm1[m], e1W2[(8 + p) * 4 + m], b);
            }
            hO[k] = fmaxf(a, 0.0f);   // h0 init (slot layout)
            hE[k] = hO[k];
            h1v[k] = fmaxf(b, 0.0f);  // h1 init
        }
        float a = e2b2[u], b = e2b2[8 + u];
#pragma unroll
        for (int m = 0; m < 4; ++m) {
            a = fmaf(hm2[m], e2W2[u * 4 + m], a);
            b = fmaf(hm2[m], e2W2[(8 + u) * 4 + m], b);
        }
        c0 = fmaxf(a, 0.0f);
        c1 = fmaxf(b, 0.0f);
    }

    float* outp = out + (size_t)hsel * T_STEPS * NB * 4 + (size_t)n * 4 + dr;
    const bool doStore = (q < 8);
    const v2f zero2 = mkv2(0.0f, 0.0f);

    // one gate per lane; quad gather + combine (all R4-proven patterns)
    auto gates = [&](float A, float& c) -> float {
        float v = fmaf(frcp(1.0f + fexp2(A)), mul, add);   // sig | tanh per gate
        const float xq1 = dppf<0xB1>(v);
        const float xq2 = dppf<0x4E>(v);
        const float xq3 = dppf<0x1B>(v);
        const float t1 = v * xq2, t2 = xq1 * xq3;
        const float P  = gb0 ? t2 : t1;           // sig(i)*tanh(g)
        const float S1 = gb0 ? xq2 : xq3;
        const float S2 = gb0 ? v   : xq1;
        const float sf = gb1 ? S1 : S2;
        const float so = gb1 ? S2 : S1;
        c = fmaf(sf, c, P);
        const float rr  = frcp(1.0f + fexp2(c * (-2.0f * LOG2E)));
        const float so2 = so + so;
        return fmaf(so2, rr, -so);                // so * tanh(c)
    };

    // L0(t): x(t) + h0(t-1) [Rs] -> h0(t) [Ws]
    auto L0body = [&](const float4& lo, const float4& hi,
                      const float (&Rs)[8], float (&Ws)[8]) {
        const v2f X0 = mkv2(lo.x, lo.y), X1 = mkv2(lo.z, lo.w);
        const v2f X2 = mkv2(hi.x, hi.y), X3 = mkv2(hi.z, hi.w);
        const v2f H0 = mkv2(Rs[0], Rs[1]), H1 = mkv2(Rs[2], Rs[3]);
        const v2f H2 = mkv2(Rs[4], Rs[5]), H3 = mkv2(Rs[6], Rs[7]);
        v2f pa = pkfma(X0, wx0[0], vb0);
        pa = pkfma(X1, wx0[1], pa);
        pa = pkfma(H0, wh0[0], pa);
        pa = pkfma(H1, wh0[1], pa);
        v2f qa = pkfma(X2, wx0[2], zero2);
        qa = pkfma(X3, wx0[3], qa);
        qa = pkfma(H2, wh0[2], qa);
        qa = pkfma(H3, wh0[3], qa);
        v2f sa = pa + qa;
        const float hu = gates(sa.x + sa.y, c0);
        const float hsw = swzx16(hu);
        Ws[0] = hu;  Ws[1] = dppf<0x124>(hu);  Ws[2] = dppf<0x128>(hu);  Ws[3] = dppf<0x12C>(hu);
        Ws[4] = hsw; Ws[5] = dppf<0x124>(hsw); Ws[6] = dppf<0x128>(hsw); Ws[7] = dppf<0x12C>(hsw);
    };

    // L1(t-1)+dec+store: consumes h0(t-1) [Rs] + h1 state in place
    auto L1decBody = [&](const float (&Rs)[8], float* op) {
        const v2f H0 = mkv2(Rs[0], Rs[1]), H1 = mkv2(Rs[2], Rs[3]);
        const v2f H2 = mkv2(Rs[4], Rs[5]), H3 = mkv2(Rs[6], Rs[7]);
        const v2f G0 = mkv2(h1v[0], h1v[1]), G1 = mkv2(h1v[2], h1v[3]);
        const v2f G2 = mkv2(h1v[4], h1v[5]), G3 = mkv2(h1v[6], h1v[7]);
        v2f pa = pkfma(H0, wx1[0], vb1);
        pa = pkfma(H1, wx1[1], pa);
        pa = pkfma(G0, wh1[0], pa);
        pa = pkfma(G1, wh1[1], pa);
        v2f qa = pkfma(H2, wx1[2], zero2);
        qa = pkfma(H3, wx1[3], qa);
        qa = pkfma(G2, wh1[2], qa);
        qa = pkfma(G3, wh1[3], qa);
        v2f sa = pa + qa;
        const float hu = gates(sa.x + sa.y, c1);
        const float hsw = swzx16(hu);
        h1v[0] = hu;  h1v[1] = dppf<0x124>(hu);  h1v[2] = dppf<0x128>(hu);  h1v[3] = dppf<0x12C>(hu);
        h1v[4] = hsw; h1v[5] = dppf<0x124>(hsw); h1v[6] = dppf<0x128>(hsw); h1v[7] = dppf<0x12C>(hsw);
        // decoder + heads (R4-proven quad rotations)
        v2f dd = pkfma(mkv2(h1v[0], h1v[1]), dwr2[0], vdb);
        dd = pkfma(mkv2(h1v[2], h1v[3]), dwr2[1], dd);
        v2f de = pkfma(mkv2(h1v[4], h1v[5]), dwr2[2], zero2);
        de = pkfma(mkv2(h1v[6], h1v[7]), dwr2[3], de);
        v2f ds = dd + de;
        float da = fmaxf(ds.x + ds.y, 0.0f);
        const float d1 = dppf<0x39>(da);
        const float d2 = dppf<0x4E>(da);
        const float d3 = dppf<0x93>(da);
        float o = fb;
        o = fmaf(da, fwp[0], o); o = fmaf(d1, fwp[1], o);
        o = fmaf(d2, fwp[2], o); o = fmaf(d3, fwp[3], o);
        if (doStore) *op = o;
    };

    // consume slot, reload SAME slot with x(t+4), then L1(t-1)+dec+store.
#define SUBSTEP(XA, XB, Rs, Ws, LP)                                       \
    L0body(XA, XB, Rs, Ws);                                               \
    XA = (LP)[0]; XB = (LP)[1];                                           \
    L1decBody(Rs, outp); outp += (size_t)NB * 4;

#define SUBTAIL(XA, XB, Rs, Ws)                                           \
    L0body(XA, XB, Rs, Ws);                                               \
    L1decBody(Rs, outp); outp += (size_t)NB * 4;

    // prologue: t=0 (L0 only); slot0 reloads x4.
    L0body(x0a, x0b, hO, hE);
    x0a = dp[4 * TS4]; x0b = dp[4 * TS4 + 1];

    // main: k=0..248, sub-step i handles t=4k+1+i (slot (1+i)&3), loads x(t+4).
    const float4* pf = dp + 5 * TS4;
    for (int k = 0; k < 249; ++k) {
        const float4* pb = pf;
        const float4* p3 = (k == 248) ? dp : (pb + 3 * TS4);  // clamp x(1000)
        SUBSTEP(x1a, x1b, hE, hO, pb + 0 * TS4)   // t = 4k+1 (odd)
        SUBSTEP(x2a, x2b, hO, hE, pb + 1 * TS4)   // t = 4k+2
        SUBSTEP(x3a, x3b, hE, hO, pb + 2 * TS4)   // t = 4k+3
        SUBSTEP(x0a, x0b, hO, hE, p3)             // t = 4k+4
        pf += 4 * TS4;
    }
    // tail: t=997,998,999 (slots 1..3 already loaded)
    SUBTAIL(x1a, x1b, hE, hO)   // 997
    SUBTAIL(x2a, x2b, hO, hE)   // 998
    SUBTAIL(x3a, x3b, hE, hO)   // 999
    // epilogue: L1(999)+dec+store (h0(999) sits in hO)
    L1decBody(hO, outp);

#undef SUBSTEP
#undef SUBTAIL
}

} // namespace

extern "C" void kernel_launch(void* const* d_in, const int* in_sizes, int n_in,
                              void* d_out, int out_size, void* d_ws, size_t ws_size,
                              hipStream_t stream) {
    const float* state = (const float*)d_in[0];
    const float* dist  = (const float*)d_in[1];
    const float* e1W1  = (const float*)d_in[2];
    const float* e1b1  = (const float*)d_in[3];
    const float* e1W2  = (const float*)d_in[4];
    const float* e1b2  = (const float*)d_in[5];
    const float* e2W1  = (const float*)d_in[6];
    const float* e2b1  = (const float*)d_in[7];
    const float* e2W2  = (const float*)d_in[8];
    const float* e2b2  = (const float*)d_in[9];
    const float* Wih0  = (const float*)d_in[10];
    const float* Whh0  = (const float*)d_in[11];
    const float* bih0  = (const float*)d_in[12];
    const float* bhh0  = (const float*)d_in[13];
    const float* Wih1  = (const float*)d_in[14];
    const float* Whh1  = (const float*)d_in[15];
    const float* bih1  = (const float*)d_in[16];
    const float* bhh1  = (const float*)d_in[17];
    const float* decW  = (const float*)d_in[18];
    const float* decb  = (const float*)d_in[19];
    const float* finW  = (const float*)d_in[20];
    const float* finb  = (const float*)d_in[21];
    const float* fin2W = (const float*)d_in[22];
    const float* fin2b = (const float*)d_in[23];
    float* outp = (float*)d_out;

    lstm_fused_kernel<<<dim3(NB / 8), dim3(256), 0, stream>>>(
        state, dist,
        e1W1, e1b1, e1W2, e1b2,
        e2W1, e2b1, e2W2, e2b2,
        Wih0, Whh0, bih0, bhh0,
        Wih1, Whh1, bih1, bhh1,
        decW, decb, finW, finb, fin2W, fin2b,
        outp);
}

// Round 12
// 299.693 us; speedup vs baseline: 1.5512x; 1.5512x over previous
//
#include <hip/hip_runtime.h>

namespace {

constexpr int T_STEPS = 1000;
constexpr int NB      = 4096;
constexpr float LOG2E = 1.4426950408889634f;

typedef float v2f __attribute__((ext_vector_type(2)));

__device__ __forceinline__ float fexp2(float x) { return __builtin_amdgcn_exp2f(x); }
__device__ __forceinline__ float frcp(float x)  { return __builtin_amdgcn_rcpf(x); }
__device__ __forceinline__ v2f mkv2(float a, float b) { v2f r; r.x = a; r.y = b; return r; }

__device__ __forceinline__ v2f pkfma(v2f a, v2f b, v2f c) {
#if __has_builtin(__builtin_elementwise_fma)
    return __builtin_elementwise_fma(a, b, c);   // v_pk_fma_f32
#else
    v2f r; r.x = fmaf(a.x, b.x, c.x); r.y = fmaf(a.y, b.y, c.y); return r;
#endif
}

// DPP on the VALU pipe (R3/R6-HW-proven patterns).
template<int CTRL>
__device__ __forceinline__ float dppf(float v) {
    int i = __float_as_int(v);
    return __int_as_float(__builtin_amdgcn_update_dpp(i, i, CTRL, 0xF, 0xF, false));
}

// R9 structure (best measured: 294us, VALU pipe 77% busy) + decoder skew:
// per substep s, THREE independent chains run in one instruction stream:
//   L0(s)      : x(s) + h0(s-1)          -> h0(s)
//   dec(s-2)   : h1(s-2) (pre-overwrite) -> store out(s-2)
//   L1(s-1)    : h0(s-1) + h1(s-2)       -> h1(s-1)
// dec no longer sits on L1's critical tail. Zero added instructions.
// W=16 (1 wave/SIMD structural), pk_fma matvecs, v_rcp/v_exp kept (R10 A/B),
// distance-8 consume-then-reload x-slot prefetch (R9), hE/hO ping-pong.
__global__ __launch_bounds__(256, 1)
void lstm_fused_kernel(
    const float* __restrict__ state, const float* __restrict__ dist,
    const float* __restrict__ e1W1, const float* __restrict__ e1b1,
    const float* __restrict__ e1W2, const float* __restrict__ e1b2,
    const float* __restrict__ e2W1, const float* __restrict__ e2b1,
    const float* __restrict__ e2W2, const float* __restrict__ e2b2,
    const float* __restrict__ Wih0, const float* __restrict__ Whh0,
    const float* __restrict__ bih0, const float* __restrict__ bhh0,
    const float* __restrict__ Wih1, const float* __restrict__ Whh1,
    const float* __restrict__ bih1, const float* __restrict__ bhh1,
    const float* __restrict__ decW, const float* __restrict__ decb,
    const float* __restrict__ finW, const float* __restrict__ finb,
    const float* __restrict__ fin2W, const float* __restrict__ fin2b,
    float* __restrict__ out)
{
    const int tid = (int)threadIdx.x;
    const int q   = tid & 15;
    const int n   = blockIdx.x * 16 + (tid >> 4);
    const int u   = q & 7;
    const int hlf = q >> 3;
    const int r0  = hlf * 16 + u;   // row A (i_u | g_u)
    const int r1  = r0 + 8;         // row B (f_u | o_u)

    // probe row_ror direction once: slot k holds h[(u+sgn*k)&7]
    const int pv  = __builtin_amdgcn_update_dpp(0, q, 0x121, 0xF, 0xF, true);
    const int sgn = (pv == ((q + 1) & 15)) ? 1 : -1;
    auto pidx = [&](int k) { return (u + sgn * k) & 7; };

    const float sA   = hlf ? (-2.0f * LOG2E) : (-LOG2E);   // row A: sigmoid | tanh
    const float sB   = -LOG2E;                              // row B always sigmoid
    const float mulA = hlf ? 2.0f : 1.0f;
    const float addA = hlf ? -1.0f : 0.0f;

    // ---- packed weight rows (h-side in rotated slot layout; R9-verbatim) ----
    v2f wx0a[4], wh0a[4], wx0b[4], wh0b[4];
    v2f wx1a[4], wh1a[4], wx1b[4], wh1b[4];
#pragma unroll
    for (int k = 0; k < 4; ++k) {
        const int k0 = 2 * k, k1 = 2 * k + 1;
        const int p0 = pidx(k0), p1 = pidx(k1);
        wx0a[k] = mkv2(Wih0[r0 * 8 + k0] * sA, Wih0[r0 * 8 + k1] * sA);
        wh0a[k] = mkv2(Whh0[r0 * 8 + p0] * sA, Whh0[r0 * 8 + p1] * sA);
        wx0b[k] = mkv2(Wih0[r1 * 8 + k0] * sB, Wih0[r1 * 8 + k1] * sB);
        wh0b[k] = mkv2(Whh0[r1 * 8 + p0] * sB, Whh0[r1 * 8 + p1] * sB);
        wx1a[k] = mkv2(Wih1[r0 * 8 + p0] * sA, Wih1[r0 * 8 + p1] * sA);
        wh1a[k] = mkv2(Whh1[r0 * 8 + p0] * sA, Whh1[r0 * 8 + p1] * sA);
        wx1b[k] = mkv2(Wih1[r1 * 8 + p0] * sB, Wih1[r1 * 8 + p1] * sB);
        wh1b[k] = mkv2(Whh1[r1 * 8 + p0] * sB, Whh1[r1 * 8 + p1] * sB);
    }
    const v2f vbA0 = mkv2((bih0[r0] + bhh0[r0]) * sA, 0.0f);
    const v2f vbB0 = mkv2((bih0[r1] + bhh0[r1]) * sB, 0.0f);
    const v2f vbA1 = mkv2((bih1[r0] + bhh1[r0]) * sA, 0.0f);
    const v2f vbB1 = mkv2((bih1[r1] + bhh1[r1]) * sB, 0.0f);

    // decoder (R9-verbatim)
    const int dr = q & 3;
    v2f dwr2[4];
#pragma unroll
    for (int k = 0; k < 4; ++k)
        dwr2[k] = mkv2(decW[dr * 8 + pidx(2 * k)], decW[dr * 8 + pidx(2 * k + 1)]);
    const v2f vdb = mkv2(decb[dr], 0.0f);
    float fwp[4]; float fb;
    {
        const float* Wp = (u < 4) ? finW : fin2W;
        const float* bp = (u < 4) ? finb : fin2b;
        const int oo = u & 3;
#pragma unroll
        for (int jj = 0; jj < 4; ++jj) fwp[jj] = Wp[oo * 4 + ((dr + jj) & 3)];
        fb = bp[oo];
    }

    // ---------------- x slots: issue x(0..7) loads first ----------------
    const float4* dp = reinterpret_cast<const float4*>(dist) + (size_t)n * 2;
    constexpr size_t TS4 = (size_t)NB * 2;
    float4 x0a = dp[0 * TS4], x0b = dp[0 * TS4 + 1];
    float4 x1a = dp[1 * TS4], x1b = dp[1 * TS4 + 1];
    float4 x2a = dp[2 * TS4], x2b = dp[2 * TS4 + 1];
    float4 x3a = dp[3 * TS4], x3b = dp[3 * TS4 + 1];
    float4 x4a = dp[4 * TS4], x4b = dp[4 * TS4 + 1];
    float4 x5a = dp[5 * TS4], x5b = dp[5 * TS4 + 1];
    float4 x6a = dp[6 * TS4], x6b = dp[6 * TS4 + 1];
    float4 x7a = dp[7 * TS4], x7b = dp[7 * TS4 + 1];

    // ---------------- encoders (R9-verbatim; overlaps loads) ----------------
    v2f hE0, hE1, hE2, hE3;       // h0 at even t
    v2f hO0, hO1, hO2, hO3;       // h0 at odd t (init = h0(-1))
    v2f h10, h11, h12, h13;       // h1 state
    float c0, c1;
    {
        float s[16];
#pragma unroll
        for (int k = 0; k < 16; ++k) s[k] = state[n * 16 + k];
        float hm1[4], hm2[4];
#pragma unroll
        for (int m = 0; m < 4; ++m) {
            float a = e1b1[m], b = e2b1[m];
#pragma unroll
            for (int k = 0; k < 16; ++k) {
                a = fmaf(s[k], e1W1[m * 16 + k], a);
                b = fmaf(s[k], e2W1[m * 16 + k], b);
            }
            hm1[m] = fmaxf(a, 0.0f); hm2[m] = fmaxf(b, 0.0f);
        }
        float h0s[8], h1s[8];
#pragma unroll
        for (int k = 0; k < 8; ++k) {
            const int p = pidx(k);
            float a = e1b2[p], b = e1b2[8 + p];
#pragma unroll
            for (int m = 0; m < 4; ++m) {
                a = fmaf(hm1[m], e1W2[p * 4 + m], a);
                b = fmaf(hm1[m], e1W2[(8 + p) * 4 + m], b);
            }
            h0s[k] = fmaxf(a, 0.0f);
            h1s[k] = fmaxf(b, 0.0f);
        }
        float a = e2b2[u], b = e2b2[8 + u];
#pragma unroll
        for (int m = 0; m < 4; ++m) {
            a = fmaf(hm2[m], e2W2[u * 4 + m], a);
            b = fmaf(hm2[m], e2W2[(8 + u) * 4 + m], b);
        }
        c0 = fmaxf(a, 0.0f);
        c1 = fmaxf(b, 0.0f);
        hO0 = mkv2(h0s[0], h0s[1]); hO1 = mkv2(h0s[2], h0s[3]);
        hO2 = mkv2(h0s[4], h0s[5]); hO3 = mkv2(h0s[6], h0s[7]);
        hE0 = hO0; hE1 = hO1; hE2 = hO2; hE3 = hO3;
        h10 = mkv2(h1s[0], h1s[1]); h11 = mkv2(h1s[2], h1s[3]);
        h12 = mkv2(h1s[4], h1s[5]); h13 = mkv2(h1s[6], h1s[7]);
    }

    float* outp = out + ((u < 4) ? ((size_t)n * 4 + u)
                                 : ((size_t)T_STEPS * NB * 4 + (size_t)n * 4 + (u - 4)));
    const bool doStore = (q < 8);
    const v2f zero2 = mkv2(0.0f, 0.0f);

    // L0(t): x(t) + h0(t-1) [read regs] -> h0(t) [write regs]. One chain.
    auto L0body = [&](const float4& lo, const float4& hi,
                      const v2f& R0, const v2f& R1, const v2f& R2, const v2f& R3,
                      v2f& W0, v2f& W1, v2f& W2, v2f& W3) {
        const v2f X0 = mkv2(lo.x, lo.y), X1 = mkv2(lo.z, lo.w);
        const v2f X2 = mkv2(hi.x, hi.y), X3 = mkv2(hi.z, hi.w);
        v2f pa = pkfma(X0, wx0a[0], vbA0);
        pa = pkfma(X1, wx0a[1], pa);
        pa = pkfma(R0, wh0a[0], pa);
        pa = pkfma(R1, wh0a[1], pa);
        v2f qa = pkfma(X2, wx0a[2], zero2);
        qa = pkfma(X3, wx0a[3], qa);
        qa = pkfma(R2, wh0a[2], qa);
        qa = pkfma(R3, wh0a[3], qa);
        v2f sa = pa + qa;
        const float A = sa.x + sa.y;
        v2f pb = pkfma(X0, wx0b[0], vbB0);
        pb = pkfma(X1, wx0b[1], pb);
        pb = pkfma(R0, wh0b[0], pb);
        pb = pkfma(R1, wh0b[1], pb);
        v2f qb = pkfma(X2, wx0b[2], zero2);
        qb = pkfma(X3, wx0b[3], qb);
        qb = pkfma(R2, wh0b[2], qb);
        qb = pkfma(R3, wh0b[3], qb);
        v2f sb = pb + qb;
        const float B = sb.x + sb.y;
        float a0 = fmaf(frcp(1.0f + fexp2(A)), mulA, addA);  // sig(i)|tanh(g)
        float a1 = frcp(1.0f + fexp2(B));                     // sig(f)|sig(o)
        const float s0 = dppf<0x128>(a0);
        const float s1 = dppf<0x128>(a1);
        const float prod = a0 * s0;
        const float fg = hlf ? s1 : a1;
        const float og = hlf ? a1 : s1;
        c0 = fmaf(fg, c0, prod);
        const float rr  = frcp(1.0f + fexp2(c0 * (-2.0f * LOG2E)));
        const float og2 = og + og;
        const float hn  = fmaf(og2, rr, -og);                 // og * tanh(c0)
        const float t1 = dppf<0x121>(hn), t2 = dppf<0x122>(hn), t3 = dppf<0x123>(hn);
        const float t4 = dppf<0x124>(hn), t5 = dppf<0x125>(hn), t6 = dppf<0x126>(hn);
        const float t7 = dppf<0x127>(hn);
        W0 = mkv2(hn, t1); W1 = mkv2(t2, t3);
        W2 = mkv2(t4, t5); W3 = mkv2(t6, t7);
    };

    // dec(t-2): reads the CURRENT h1 regs (= h1(t-2), pre-overwrite), stores.
    auto decBody = [&](float* op) {
        v2f dd = pkfma(h10, dwr2[0], vdb);
        dd = pkfma(h11, dwr2[1], dd);
        v2f de = pkfma(h12, dwr2[2], zero2);
        de = pkfma(h13, dwr2[3], de);
        v2f ds = dd + de;
        float da = fmaxf(ds.x + ds.y, 0.0f);
        const float d1 = dppf<0x39>(da);
        const float d2 = dppf<0x4E>(da);
        const float d3 = dppf<0x93>(da);
        float o = fb;
        o = fmaf(da, fwp[0], o); o = fmaf(d1, fwp[1], o);
        o = fmaf(d2, fwp[2], o); o = fmaf(d3, fwp[3], o);
        if (doStore) *op = o;
    };

    // L1(t-1): h0(t-1) [R regs] + h1(t-2) -> h1(t-1). No decoder tail.
    auto L1body = [&](const v2f& R0, const v2f& R1, const v2f& R2, const v2f& R3) {
        v2f pa = pkfma(R0, wx1a[0], vbA1);
        pa = pkfma(R1, wx1a[1], pa);
        pa = pkfma(h10, wh1a[0], pa);
        pa = pkfma(h11, wh1a[1], pa);
        v2f qa = pkfma(R2, wx1a[2], zero2);
        qa = pkfma(R3, wx1a[3], qa);
        qa = pkfma(h12, wh1a[2], qa);
        qa = pkfma(h13, wh1a[3], qa);
        v2f sa = pa + qa;
        const float A = sa.x + sa.y;
        v2f pb = pkfma(R0, wx1b[0], vbB1);
        pb = pkfma(R1, wx1b[1], pb);
        pb = pkfma(h10, wh1b[0], pb);
        pb = pkfma(h11, wh1b[1], pb);
        v2f qb = pkfma(R2, wx1b[2], zero2);
        qb = pkfma(R3, wx1b[3], qb);
        qb = pkfma(h12, wh1b[2], qb);
        qb = pkfma(h13, wh1b[3], qb);
        v2f sb = pb + qb;
        const float B = sb.x + sb.y;
        float a0 = fmaf(frcp(1.0f + fexp2(A)), mulA, addA);
        float a1 = frcp(1.0f + fexp2(B));
        const float s0 = dppf<0x128>(a0);
        const float s1 = dppf<0x128>(a1);
        const float prod = a0 * s0;
        const float fg = hlf ? s1 : a1;
        const float og = hlf ? a1 : s1;
        c1 = fmaf(fg, c1, prod);
        const float rr  = frcp(1.0f + fexp2(c1 * (-2.0f * LOG2E)));
        const float og2 = og + og;
        const float hn  = fmaf(og2, rr, -og);
        const float t1 = dppf<0x121>(hn), t2 = dppf<0x122>(hn), t3 = dppf<0x123>(hn);
        const float t4 = dppf<0x124>(hn), t5 = dppf<0x125>(hn), t6 = dppf<0x126>(hn);
        const float t7 = dppf<0x127>(hn);
        h10 = mkv2(hn, t1); h11 = mkv2(t2, t3);
        h12 = mkv2(t4, t5); h13 = mkv2(t6, t7);
    };

    // substep s: L0(s); reload slot with x(s+8); dec(s-2); L1(s-1).
#define SUBSTEP(XA, XB, R0, R1, R2, R3, W0, W1, W2, W3, LP)               \
    L0body(XA, XB, R0, R1, R2, R3, W0, W1, W2, W3);                       \
    XA = (LP)[0]; XB = (LP)[1];                                           \
    decBody(outp); outp += (size_t)NB * 4;                                \
    L1body(R0, R1, R2, R3);

#define SUBTAIL(XA, XB, R0, R1, R2, R3, W0, W1, W2, W3)                   \
    L0body(XA, XB, R0, R1, R2, R3, W0, W1, W2, W3);                       \
    decBody(outp); outp += (size_t)NB * 4;                                \
    L1body(R0, R1, R2, R3);

    // s=0: L0(0) only; slot0 reloads x8.
    L0body(x0a, x0b, hO0, hO1, hO2, hO3, hE0, hE1, hE2, hE3);
    x0a = dp[8 * TS4]; x0b = dp[8 * TS4 + 1];
    // s=1 (peeled): L0(1) + L1(0); no dec yet. slot1 reloads x9.
    L0body(x1a, x1b, hE0, hE1, hE2, hE3, hO0, hO1, hO2, hO3);
    x1a = dp[9 * TS4]; x1b = dp[9 * TS4 + 1];
    L1body(hE0, hE1, hE2, hE3);

    // main: k=0..123, substeps s=8k+2..8k+9 (slots 2,3,4,5,6,7,0,1),
    // reload x(s+8); store out(s-2). Last block clamps x1000/x1001.
    const float4* pf = dp + 10 * TS4;
    for (int k = 0; k < 124; ++k) {
        const float4* pb = pf;
        const float4* p6 = (k == 123) ? dp : (pb + 6 * TS4);  // x(1000) clamp
        const float4* p7 = (k == 123) ? dp : (pb + 7 * TS4);  // x(1001) clamp
        SUBSTEP(x2a, x2b, hO0, hO1, hO2, hO3, hE0, hE1, hE2, hE3, pb + 0 * TS4)
        SUBSTEP(x3a, x3b, hE0, hE1, hE2, hE3, hO0, hO1, hO2, hO3, pb + 1 * TS4)
        SUBSTEP(x4a, x4b, hO0, hO1, hO2, hO3, hE0, hE1, hE2, hE3, pb + 2 * TS4)
        SUBSTEP(x5a, x5b, hE0, hE1, hE2, hE3, hO0, hO1, hO2, hO3, pb + 3 * TS4)
        SUBSTEP(x6a, x6b, hO0, hO1, hO2, hO3, hE0, hE1, hE2, hE3, pb + 4 * TS4)
        SUBSTEP(x7a, x7b, hE0, hE1, hE2, hE3, hO0, hO1, hO2, hO3, pb + 5 * TS4)
        SUBSTEP(x0a, x0b, hO0, hO1, hO2, hO3, hE0, hE1, hE2, hE3, p6)
        SUBSTEP(x1a, x1b, hE0, hE1, hE2, hE3, hO0, hO1, hO2, hO3, p7)
        pf += 8 * TS4;
    }
    // tail: s=994..999 (slots 2..7 hold x994..x999; no loads)
    SUBTAIL(x2a, x2b, hO0, hO1, hO2, hO3, hE0, hE1, hE2, hE3)   // s=994
    SUBTAIL(x3a, x3b, hE0, hE1, hE2, hE3, hO0, hO1, hO2, hO3)   // s=995
    SUBTAIL(x4a, x4b, hO0, hO1, hO2, hO3, hE0, hE1, hE2, hE3)   // s=996
    SUBTAIL(x5a, x5b, hE0, hE1, hE2, hE3, hO0, hO1, hO2, hO3)   // s=997
    SUBTAIL(x6a, x6b, hO0, hO1, hO2, hO3, hE0, hE1, hE2, hE3)   // s=998
    SUBTAIL(x7a, x7b, hE0, hE1, hE2, hE3, hO0, hO1, hO2, hO3)   // s=999
    // epilogue: dec(998); L1(999) using h0(999)=hO; dec(999).
    decBody(outp); outp += (size_t)NB * 4;
    L1body(hO0, hO1, hO2, hO3);
    decBody(outp);

#undef SUBSTEP
#undef SUBTAIL
}

} // namespace

extern "C" void kernel_launch(void* const* d_in, const int* in_sizes, int n_in,
                              void* d_out, int out_size, void* d_ws, size_t ws_size,
                              hipStream_t stream) {
    const float* state = (const float*)d_in[0];
    const float* dist  = (const float*)d_in[1];
    const float* e1W1  = (const float*)d_in[2];
    const float* e1b1  = (const float*)d_in[3];
    const float* e1W2  = (const float*)d_in[4];
    const float* e1b2  = (const float*)d_in[5];
    const float* e2W1  = (const float*)d_in[6];
    const float* e2b1  = (const float*)d_in[7];
    const float* e2W2  = (const float*)d_in[8];
    const float* e2b2  = (const float*)d_in[9];
    const float* Wih0  = (const float*)d_in[10];
    const float* Whh0  = (const float*)d_in[11];
    const float* bih0  = (const float*)d_in[12];
    const float* bhh0  = (const float*)d_in[13];
    const float* Wih1  = (const float*)d_in[14];
    const float* Whh1  = (const float*)d_in[15];
    const float* bih1  = (const float*)d_in[16];
    const float* bhh1  = (const float*)d_in[17];
    const float* decW  = (const float*)d_in[18];
    const float* decb  = (const float*)d_in[19];
    const float* finW  = (const float*)d_in[20];
    const float* finb  = (const float*)d_in[21];
    const float* fin2W = (const float*)d_in[22];
    const float* fin2b = (const float*)d_in[23];
    float* outp = (float*)d_out;

    lstm_fused_kernel<<<dim3(NB / 16), dim3(256), 0, stream>>>(
        state, dist,
        e1W1, e1b1, e1W2, e1b2,
        e2W1, e2b1, e2W2, e2b2,
        Wih0, Whh0, bih0, bhh0,
        Wih1, Whh1, bih1, bhh1,
        decW, decb, finW, finb, fin2W, fin2b,
        outp);
}